// Round 7
// baseline (52.655 us; speedup 1.0000x reference)
//
#include <hip/hip_runtime.h>

#define HH 128
#define WW 128
#define CC 64
#define KD 16
#define HW (HH * WW)
#define HWB (HW * 4)
#define TOTBYTES (4u * CC * HW * 4u)   // B=4 * C=64 * H*W * 4B = 16.78 MB
#define OOB_SENT 0x40000000            // always-OOB voffset -> HW returns 0

typedef __attribute__((ext_vector_type(4))) int   int32x4_t;
typedef __attribute__((ext_vector_type(4))) float floatx4;
typedef __attribute__((ext_vector_type(2))) float floatx2;

__device__ floatx4 llvm_amdgcn_raw_buffer_load_v4f32(int32x4_t srsrc, int voffset,
                                                     int soffset, int aux)
    __asm("llvm.amdgcn.raw.buffer.load.v4f32");
__device__ float llvm_amdgcn_raw_buffer_load_f32(int32x4_t srsrc, int voffset,
                                                 int soffset, int aux)
    __asm("llvm.amdgcn.raw.buffer.load.f32");

__device__ inline int32x4_t make_srd(const void* p, unsigned bytes) {
    const unsigned long long a = (unsigned long long)p;
    int32x4_t r;
    r.x = (int)(a & 0xffffffffull);
    r.y = (int)(a >> 32);
    r.z = (int)bytes;
    r.w = 0x00020000;
    return r;
}

#if __has_builtin(__builtin_amdgcn_exp2f)
#define FAST_EXP2(x) __builtin_amdgcn_exp2f(x)
#define KLOG2E 1.44269504088896340736f
#else
#define FAST_EXP2(x) __expf(x)
#define KLOG2E 1.0f
#endif

// Block: 512 threads = 8 waves over one 16(w) x 4(h) pixel tile.
// Phase 0: stage Wk (36 KB) -> LDS repacked [g][ci][t][d16] (d-pairs contiguous).
// Phase 1: wave g reads channels [8g,8g+8) of x (double-buffered dwordx4 rows),
//          accumulates partial k for all 16 d as 8 packed float2 accumulators
//          (v_pk_fma_f32); weights via uniform-address LDS broadcast.
// Then:    partials -> LDS (aliasing weight region), 8-way reduce -> k.
// Phase 2: q-conv + v + packed softmax for channels [8g,8g+8).
// Interior blocks (70%) take a maskless tap path (wave-uniform branch).
__global__ __launch_bounds__(512, 8) void gatev_fused(
    const float* __restrict__ x, const float* __restrict__ y,
    const float* __restrict__ z,
    const float* __restrict__ Wq, const float* __restrict__ bq,
    const float* __restrict__ Wk, const float* __restrict__ bk,
    const float* __restrict__ wv, const float* __restrict__ bv,
    float* __restrict__ out)
{
    __shared__ float wk_lds[9216];   // 36 KB; weights -> partials -> k (aliased)

    const int tid  = threadIdx.x;
    const int g    = __builtin_amdgcn_readfirstlane(tid >> 6);
    const int lane = tid & 63;
    const int px   = lane & 15, py = lane >> 4;
    const int b    = blockIdx.z;
    const int h    = blockIdx.y * 4 + py;
    const int w    = blockIdx.x * 16 + px;
    const int pix  = h * WW + w;

    const bool interior = (blockIdx.x > 0) & (blockIdx.x < 7) &
                          (blockIdx.y > 0) & (blockIdx.y < 31);

    const int32x4_t rx = make_srd(x, TOTBYTES);
    const int32x4_t ry = make_srd(y, TOTBYTES);
    const int32x4_t rz = make_srd(z, TOTBYTES);

    // One float4 per tap-row at col max(w-1,0) covers the 3 horizontal taps.
    const int colb = (w > 0 ? w - 1 : 0) * 4;
    int rowB[3];
#pragma unroll
    for (int r = 0; r < 3; ++r) {
        const int rr = h - 1 + r;
        rowB[r] = (rr >= 0 && rr < HH) ? rr * WW * 4 + colb : OOB_SENT;
    }
    const float mL = (w > 0) ? 1.f : 0.f;
    const float mR = (w < WW - 1) ? 1.f : 0.f;
    const bool  w0e = (w == 0);

    const int base = b * CC * HWB;
    const int c0   = __builtin_amdgcn_readfirstlane(g * 8);

    // ---------------- phase 0: stage Wk -> LDS [g][ci][t][d16] --------------
    // src s = (d*64 + c)*9 + t ; dst = (c>>3)*1152 + (c&7)*144 + t*16 + d
#pragma unroll
    for (int p = 0; p < 18; ++p) {
        const int s   = p * 512 + tid;           // coalesced across lanes
        const int d   = s / 576;
        const int rem = s - d * 576;
        const int c   = rem / 9;
        const int t   = rem - c * 9;
        wk_lds[(c >> 3) * 1152 + (c & 7) * 144 + t * 16 + d] = Wk[s];
    }
    __syncthreads();

    // ---------------- phase 1: packed partial k over 8 channels -------------
    floatx2 acc2[8];
#pragma unroll
    for (int p = 0; p < 8; ++p) acc2[p] = (floatx2){0.f, 0.f};

    auto load3 = [&](floatx4 (&f)[3], int so) {
#pragma unroll
        for (int r = 0; r < 3; ++r)
            f[r] = llvm_amdgcn_raw_buffer_load_v4f32(rx, rowB[r], so, 0);
    };
    auto taps3 = [&](const floatx4& f, float& tL, float& tC, float& tR) {
        if (interior) { tL = f.x; tC = f.y; tR = f.z; }
        else {
            tL = f.x * mL;
            tC = w0e ? f.x : f.y;
            tR = (w0e ? f.y : f.z) * mR;
        }
    };
    auto compute = [&](const floatx4 (&f)[3], int wb) {
        float tp[9];
#pragma unroll
        for (int r = 0; r < 3; ++r)
            taps3(f[r], tp[r * 3 + 0], tp[r * 3 + 1], tp[r * 3 + 2]);
#pragma unroll
        for (int t = 0; t < 9; ++t) {
            const floatx2 tp2 = {tp[t], tp[t]};
            const floatx2* wrow = (const floatx2*)&wk_lds[wb + t * 16]; // uniform addr
#pragma unroll
            for (int p = 0; p < 8; ++p)
                acc2[p] = __builtin_elementwise_fma(wrow[p], tp2, acc2[p]);
        }
    };

    const int wbase = g * 1152;
    floatx4 f0[3], f1[3];
    load3(f0, base + c0 * HWB);
#pragma unroll
    for (int cp = 0; cp < 4; ++cp) {
        load3(f1, base + (c0 + 2 * cp + 1) * HWB);       // prefetch odd channel
        compute(f0, wbase + (2 * cp) * 144);
        load3(f0, base + (c0 + 2 * cp + 2) * HWB);       // prefetch next even (tail SRD-bounded)
        compute(f1, wbase + (2 * cp + 1) * 144);
    }
    __syncthreads();                                     // all weight reads done

    // partials overwrite the weight region: part[g][d][lane]
#pragma unroll
    for (int p = 0; p < 8; ++p) {
        wk_lds[g * 1024 + (2 * p + 0) * 64 + lane] = acc2[p].x;
        wk_lds[g * 1024 + (2 * p + 1) * 64 + lane] = acc2[p].y;
    }
    __syncthreads();

    // ---------------- reduce 8 partials -> k[d][px64] (in place) ------------
#pragma unroll
    for (int rep = 0; rep < 2; ++rep) {
        const int idx = tid + rep * 512;                 // = d*64 + px64
        float s = wk_lds[idx];
#pragma unroll
        for (int gg = 1; gg < 8; ++gg) s += wk_lds[gg * 1024 + idx];
        const int d = idx >> 6;                          // wave-uniform
        wk_lds[idx] = fmaxf(s + bk[d], 0.f) * KLOG2E;
    }
    __syncthreads();

    // ---------------- phase 2: q, v, packed softmax, 8 c's per wave ---------
    floatx2 qp[4], zp[4];
#pragma unroll 2
    for (int ci = 0; ci < 8; ++ci) {
        const int c  = c0 + ci;
        const int so = base + c * HWB;
        const float* wq = Wq + c * 9;                    // uniform -> s_load
        float a = 0.f;
#pragma unroll
        for (int r = 0; r < 3; ++r) {
            const floatx4 f = llvm_amdgcn_raw_buffer_load_v4f32(ry, rowB[r], so, 0);
            float tL, tC, tR;
            taps3(f, tL, tC, tR);
            a = fmaf(wq[r * 3 + 0], tL, a);
            a = fmaf(wq[r * 3 + 1], tC, a);
            a = fmaf(wq[r * 3 + 2], tR, a);
        }
        qp[ci >> 1][ci & 1] = fmaxf(a + bq[c], 0.f);
        zp[ci >> 1][ci & 1] = llvm_amdgcn_raw_buffer_load_f32(rz, pix * 4, so, 0);
    }

    floatx2 num2[4], den2[4];
    const floatx2 zero2 = {0.f, 0.f};
#pragma unroll
    for (int p = 0; p < 4; ++p) { num2[p] = zero2; den2[p] = zero2; }

#pragma unroll
    for (int d = 0; d < KD; ++d) {
        const float kl  = wk_lds[d * 64 + lane];         // lane-contiguous, conflict-free
        const floatx2 kl2 = {kl, kl};
        const float wvd = wv[d], bvd = bv[d];            // SGPR
        const floatx2 wv2 = {wvd, wvd}, bv2 = {bvd, bvd};
#pragma unroll
        for (int p = 0; p < 4; ++p) {
            const floatx2 s2 = qp[p] * kl2;              // v_pk_mul_f32
            floatx2 e2;
            e2.x = FAST_EXP2(s2.x);
            e2.y = FAST_EXP2(s2.y);
            const floatx2 v2 = __builtin_elementwise_max(
                __builtin_elementwise_fma(zp[p], wv2, bv2), zero2);
            num2[p] = __builtin_elementwise_fma(e2, v2, num2[p]);
            den2[p] = den2[p] + e2;                      // v_pk_add_f32
        }
    }

    float* ob = out + (size_t)b * CC * HW;
#pragma unroll
    for (int ci = 0; ci < 8; ++ci)
        ob[(c0 + ci) * HW + pix] =
            __fdividef(num2[ci >> 1][ci & 1], den2[ci >> 1][ci & 1]);
}

extern "C" void kernel_launch(void* const* d_in, const int* in_sizes, int n_in,
                              void* d_out, int out_size, void* d_ws, size_t ws_size,
                              hipStream_t stream) {
    const float* x  = (const float*)d_in[0];
    const float* y  = (const float*)d_in[1];
    const float* z  = (const float*)d_in[2];
    const float* Wq = (const float*)d_in[3];
    const float* bq = (const float*)d_in[4];
    const float* Wk = (const float*)d_in[5];
    const float* bk = (const float*)d_in[6];
    const float* wv = (const float*)d_in[7];
    const float* bv = (const float*)d_in[8];
    float* out = (float*)d_out;

    dim3 grid(WW / 16, HH / 4, 4);   // 1024 blocks = 4 blocks/CU
    dim3 block(512);                 // 8 waves
    hipLaunchKernelGGL(gatev_fused, grid, block, 0, stream,
                       x, y, z, Wq, bq, Wk, bk, wv, bv, out);
}

// Round 8
// 50.492 us; speedup vs baseline: 1.0428x; 1.0428x over previous
//
#include <hip/hip_runtime.h>

#define HH 128
#define WW 128
#define CC 64
#define KD 16
#define HW (HH * WW)
#define HWB (HW * 4)
#define TOTBYTES (4u * CC * HW * 4u)   // B=4 * C=64 * H*W * 4B = 16.78 MB
#define OOB_SENT 0x40000000            // always-OOB voffset -> HW returns 0

typedef __attribute__((ext_vector_type(4))) int   int32x4_t;
typedef __attribute__((ext_vector_type(4))) float floatx4;
typedef __attribute__((ext_vector_type(2))) float floatx2;

__device__ floatx4 llvm_amdgcn_raw_buffer_load_v4f32(int32x4_t srsrc, int voffset,
                                                     int soffset, int aux)
    __asm("llvm.amdgcn.raw.buffer.load.v4f32");
__device__ float llvm_amdgcn_raw_buffer_load_f32(int32x4_t srsrc, int voffset,
                                                 int soffset, int aux)
    __asm("llvm.amdgcn.raw.buffer.load.f32");

__device__ inline int32x4_t make_srd(const void* p, unsigned bytes) {
    const unsigned long long a = (unsigned long long)p;
    int32x4_t r;
    r.x = (int)(a & 0xffffffffull);
    r.y = (int)(a >> 32);
    r.z = (int)bytes;
    r.w = 0x00020000;
    return r;
}

#if __has_builtin(__builtin_amdgcn_exp2f)
#define FAST_EXP2(x) __builtin_amdgcn_exp2f(x)
#define KLOG2E 1.44269504088896340736f
#else
#define FAST_EXP2(x) __expf(x)
#define KLOG2E 1.0f
#endif

// Block: 512 threads = 8 waves over one 16(w) x 4(h) pixel tile.
// Phase 0: stage Wk -> LDS [cg][ci][t][d16]; thread owns (d = tid&15,
//          c = tid>>4 and +32) so each ds_write has lanes spanning all 16 d
//          and 4 ci -> all 32 banks -> ~2-way conflicts (R7 had 16-way).
// Phase 1: wave g reads channels [8g,8g+8) of x (double-buffered dwordx4),
//          weights via 4x uniform ds_read_b128 per tap, 8x v_pk_fma_f32 per
//          tap into 8 packed float2 accumulators (all 16 d).
// Then:    partials -> LDS (aliasing weights), 8-way reduce -> k.
// Phase 2: q-conv + v + packed softmax for channels [8g,8g+8).
// LDS 36 KB -> 4 blocks/CU; launch_bounds(512,8) -> <=64 VGPR.
__global__ __launch_bounds__(512, 8) void gatev_fused(
    const float* __restrict__ x, const float* __restrict__ y,
    const float* __restrict__ z,
    const float* __restrict__ Wq, const float* __restrict__ bq,
    const float* __restrict__ Wk, const float* __restrict__ bk,
    const float* __restrict__ wv, const float* __restrict__ bv,
    float* __restrict__ out)
{
    __shared__ float wk_lds[9216];   // 36 KB; weights -> partials -> k (aliased)

    const int tid  = threadIdx.x;
    const int g    = __builtin_amdgcn_readfirstlane(tid >> 6);
    const int lane = tid & 63;
    const int px   = lane & 15, py = lane >> 4;
    const int b    = blockIdx.z;
    const int h    = blockIdx.y * 4 + py;
    const int w    = blockIdx.x * 16 + px;
    const int pix  = h * WW + w;

    const bool interior = (blockIdx.x > 0) & (blockIdx.x < 7) &
                          (blockIdx.y > 0) & (blockIdx.y < 31);

    const int32x4_t rx = make_srd(x, TOTBYTES);
    const int32x4_t ry = make_srd(y, TOTBYTES);
    const int32x4_t rz = make_srd(z, TOTBYTES);

    // One float4 per tap-row at col max(w-1,0) covers the 3 horizontal taps.
    const int colb = (w > 0 ? w - 1 : 0) * 4;
    int rowB[3];
#pragma unroll
    for (int r = 0; r < 3; ++r) {
        const int rr = h - 1 + r;
        rowB[r] = (rr >= 0 && rr < HH) ? rr * WW * 4 + colb : OOB_SENT;
    }
    const float mL = (w > 0) ? 1.f : 0.f;
    const float mR = (w < WW - 1) ? 1.f : 0.f;
    const bool  w0e = (w == 0);

    const int base = b * CC * HWB;
    const int c0   = __builtin_amdgcn_readfirstlane(g * 8);

    // ---------------- phase 0: stage Wk -> LDS [cg][ci][t][d16] -------------
    {
        const int d  = tid & 15;
        const int cA = tid >> 4;           // [0,32)
#pragma unroll
        for (int half = 0; half < 2; ++half) {
            const int c   = cA + half * 32;
            const int dst = (c >> 3) * 1152 + (c & 7) * 144 + d;
            const float* src = Wk + (d * CC + c) * 9;
#pragma unroll
            for (int t = 0; t < 9; ++t)
                wk_lds[dst + t * 16] = src[t];
        }
    }
    __syncthreads();

    // ---------------- phase 1: packed partial k over 8 channels -------------
    floatx2 acc2[8];
#pragma unroll
    for (int p = 0; p < 8; ++p) acc2[p] = (floatx2){0.f, 0.f};

    auto load3 = [&](floatx4 (&f)[3], int so) {
#pragma unroll
        for (int r = 0; r < 3; ++r)
            f[r] = llvm_amdgcn_raw_buffer_load_v4f32(rx, rowB[r], so, 0);
    };
    auto taps3 = [&](const floatx4& f, float& tL, float& tC, float& tR) {
        if (interior) { tL = f.x; tC = f.y; tR = f.z; }
        else {
            tL = f.x * mL;
            tC = w0e ? f.x : f.y;
            tR = (w0e ? f.y : f.z) * mR;
        }
    };
    auto compute = [&](const floatx4 (&f)[3], int wb) {
        float tp[9];
#pragma unroll
        for (int r = 0; r < 3; ++r)
            taps3(f[r], tp[r * 3 + 0], tp[r * 3 + 1], tp[r * 3 + 2]);
#pragma unroll
        for (int t = 0; t < 9; ++t) {
            const floatx2 tp2 = {tp[t], tp[t]};
#pragma unroll
            for (int j = 0; j < 4; ++j) {   // 4x uniform ds_read_b128
                const floatx4 w4 = *(const floatx4*)&wk_lds[wb + t * 16 + j * 4];
                const floatx2 lo = __builtin_shufflevector(w4, w4, 0, 1);
                const floatx2 hi = __builtin_shufflevector(w4, w4, 2, 3);
                acc2[2 * j + 0] = __builtin_elementwise_fma(lo, tp2, acc2[2 * j + 0]);
                acc2[2 * j + 1] = __builtin_elementwise_fma(hi, tp2, acc2[2 * j + 1]);
            }
        }
    };

    const int wbase = g * 1152;
    floatx4 f0[3], f1[3];
    load3(f0, base + c0 * HWB);
#pragma unroll
    for (int cp = 0; cp < 4; ++cp) {
        load3(f1, base + (c0 + 2 * cp + 1) * HWB);       // prefetch odd channel
        compute(f0, wbase + (2 * cp) * 144);
        load3(f0, base + (c0 + 2 * cp + 2) * HWB);       // prefetch next even (tail SRD-bounded)
        compute(f1, wbase + (2 * cp + 1) * 144);
    }
    __syncthreads();                                     // all weight reads done

    // partials overwrite the weight region: part[g][d][lane]; acc2[q] = d{2q,2q+1}
#pragma unroll
    for (int p = 0; p < 8; ++p) {
        wk_lds[g * 1024 + (2 * p + 0) * 64 + lane] = acc2[p].x;
        wk_lds[g * 1024 + (2 * p + 1) * 64 + lane] = acc2[p].y;
    }
    __syncthreads();

    // ---------------- reduce 8 partials -> k[d][px64] (in place) ------------
#pragma unroll
    for (int rep = 0; rep < 2; ++rep) {
        const int idx = tid + rep * 512;                 // = d*64 + px64
        float s = wk_lds[idx];
#pragma unroll
        for (int gg = 1; gg < 8; ++gg) s += wk_lds[gg * 1024 + idx];
        const int d = idx >> 6;                          // wave-uniform
        wk_lds[idx] = fmaxf(s + bk[d], 0.f) * KLOG2E;
    }
    __syncthreads();

    // ---------------- phase 2: q, v, packed softmax, 8 c's per wave ---------
    floatx2 qp[4], zp[4];
#pragma unroll 2
    for (int ci = 0; ci < 8; ++ci) {
        const int c  = c0 + ci;
        const int so = base + c * HWB;
        const float* wq = Wq + c * 9;                    // uniform -> s_load
        float a = 0.f;
#pragma unroll
        for (int r = 0; r < 3; ++r) {
            const floatx4 f = llvm_amdgcn_raw_buffer_load_v4f32(ry, rowB[r], so, 0);
            float tL, tC, tR;
            taps3(f, tL, tC, tR);
            a = fmaf(wq[r * 3 + 0], tL, a);
            a = fmaf(wq[r * 3 + 1], tC, a);
            a = fmaf(wq[r * 3 + 2], tR, a);
        }
        qp[ci >> 1][ci & 1] = fmaxf(a + bq[c], 0.f);
        zp[ci >> 1][ci & 1] = llvm_amdgcn_raw_buffer_load_f32(rz, pix * 4, so, 0);
    }

    floatx2 num2[4], den2[4];
    const floatx2 zero2 = {0.f, 0.f};
#pragma unroll
    for (int p = 0; p < 4; ++p) { num2[p] = zero2; den2[p] = zero2; }

#pragma unroll
    for (int d = 0; d < KD; ++d) {
        const float kl  = wk_lds[d * 64 + lane];         // lane-contiguous, conflict-free
        const floatx2 kl2 = {kl, kl};
        const float wvd = wv[d], bvd = bv[d];            // SGPR
        const floatx2 wv2 = {wvd, wvd}, bv2 = {bvd, bvd};
#pragma unroll
        for (int p = 0; p < 4; ++p) {
            const floatx2 s2 = qp[p] * kl2;              // v_pk_mul_f32
            floatx2 e2;
            e2.x = FAST_EXP2(s2.x);
            e2.y = FAST_EXP2(s2.y);
            const floatx2 v2 = __builtin_elementwise_max(
                __builtin_elementwise_fma(zp[p], wv2, bv2), zero2);
            num2[p] = __builtin_elementwise_fma(e2, v2, num2[p]);
            den2[p] = den2[p] + e2;                      // v_pk_add_f32
        }
    }

    float* ob = out + (size_t)b * CC * HW;
#pragma unroll
    for (int ci = 0; ci < 8; ++ci)
        ob[(c0 + ci) * HW + pix] =
            __fdividef(num2[ci >> 1][ci & 1], den2[ci >> 1][ci & 1]);
}

extern "C" void kernel_launch(void* const* d_in, const int* in_sizes, int n_in,
                              void* d_out, int out_size, void* d_ws, size_t ws_size,
                              hipStream_t stream) {
    const float* x  = (const float*)d_in[0];
    const float* y  = (const float*)d_in[1];
    const float* z  = (const float*)d_in[2];
    const float* Wq = (const float*)d_in[3];
    const float* bq = (const float*)d_in[4];
    const float* Wk = (const float*)d_in[5];
    const float* bk = (const float*)d_in[6];
    const float* wv = (const float*)d_in[7];
    const float* bv = (const float*)d_in[8];
    float* out = (float*)d_out;

    dim3 grid(WW / 16, HH / 4, 4);   // 1024 blocks = 4 blocks/CU
    dim3 block(512);                 // 8 waves
    hipLaunchKernelGGL(gatev_fused, grid, block, 0, stream,
                       x, y, z, Wq, bq, Wk, bk, wv, bv, out);
}

// Round 9
// 43.651 us; speedup vs baseline: 1.2063x; 1.1567x over previous
//
#include <hip/hip_runtime.h>

#define HH 128
#define WW 128
#define CC 64
#define KD 16
#define HW (HH * WW)
#define HWB (HW * 4)
#define TOTBYTES (4u * CC * HW * 4u)   // B=4 * C=64 * H*W * 4B = 16.78 MB
#define OOB_SENT 0x40000000            // always-OOB voffset -> HW returns 0

typedef __attribute__((ext_vector_type(4))) int   int32x4_t;
typedef __attribute__((ext_vector_type(4))) float floatx4;
typedef __attribute__((ext_vector_type(2))) float floatx2;

__device__ floatx4 llvm_amdgcn_raw_buffer_load_v4f32(int32x4_t srsrc, int voffset,
                                                     int soffset, int aux)
    __asm("llvm.amdgcn.raw.buffer.load.v4f32");
__device__ floatx2 llvm_amdgcn_raw_buffer_load_v2f32(int32x4_t srsrc, int voffset,
                                                     int soffset, int aux)
    __asm("llvm.amdgcn.raw.buffer.load.v2f32");

__device__ inline int32x4_t make_srd(const void* p, unsigned bytes) {
    const unsigned long long a = (unsigned long long)p;
    int32x4_t r;
    r.x = (int)(a & 0xffffffffull);
    r.y = (int)(a >> 32);
    r.z = (int)bytes;
    r.w = 0x00020000;
    return r;
}

#if __has_builtin(__builtin_amdgcn_exp2f)
#define FAST_EXP2(x) __builtin_amdgcn_exp2f(x)
#define KLOG2E 1.44269504088896340736f
#else
#define FAST_EXP2(x) __expf(x)
#define KLOG2E 1.0f
#endif

// Block: 512 threads = 8 waves over one 32(w) x 4(h) pixel tile.
// Each lane owns a HORIZONTAL PIXEL PAIR (w0, w0+1): one dwordx4 row-load at
// col w0-1 feeds the 3x3 taps of BOTH pixels -> x/y L1 traffic halved, and
// each uniform weight ds_read_b128 is amortized over 2 pixels -> LDS-pipe
// weight traffic per CU halved (R8's binding resource).
// Phase 0: stage Wk -> LDS [cg][ci][t][d16] (R8's conflict-free mapping).
// Phase 1: wave g: channels [8g,8g+8) of x, 16 d as 8 d-pair floatx2 accs
//          per pixel (v_pk_fma_f32); partials [g][d][p128] -> 8-way reduce.
// Phase 2: q-conv + v + softmax packed over the pixel pair.
// LDS 64 KB -> 2 blocks/CU (grid = 512 = exactly 2/CU), 16 waves/CU.
__global__ __launch_bounds__(512, 4) void gatev_fused(
    const float* __restrict__ x, const float* __restrict__ y,
    const float* __restrict__ z,
    const float* __restrict__ Wq, const float* __restrict__ bq,
    const float* __restrict__ Wk, const float* __restrict__ bk,
    const float* __restrict__ wv, const float* __restrict__ bv,
    float* __restrict__ out)
{
    __shared__ float lds[16384];   // 64 KB: Wk(36KB) -> partials(64KB) -> k(8KB)

    const int tid  = threadIdx.x;
    const int g    = __builtin_amdgcn_readfirstlane(tid >> 6);
    const int lane = tid & 63;
    const int px16 = lane & 15, py = lane >> 4;
    const int b    = blockIdx.z;
    const int w0   = blockIdx.x * 32 + px16 * 2;   // even
    const int h    = blockIdx.y * 4 + py;
    const int pix  = h * WW + w0;
    const int p0   = py * 32 + px16 * 2;           // pixel-linear in tile

    const int32x4_t rx = make_srd(x, TOTBYTES);
    const int32x4_t ry = make_srd(y, TOTBYTES);
    const int32x4_t rz = make_srd(z, TOTBYTES);

    // One float4 per tap-row at col max(w0-1,0): covers cols w0-1..w0+2,
    // i.e. all taps of the pixel pair.
    const int colb = (w0 > 0 ? w0 - 1 : 0) * 4;
    int rowB[3];
#pragma unroll
    for (int r = 0; r < 3; ++r) {
        const int rr = h - 1 + r;
        rowB[r] = (rr >= 0 && rr < HH) ? rr * WW * 4 + colb : OOB_SENT;
    }
    const float mL = (w0 > 0) ? 1.f : 0.f;           // px0 left tap
    const float mR = (w0 + 2 < WW) ? 1.f : 0.f;      // px1 right tap
    const bool  w0e = (w0 == 0);

    const int base = b * CC * HWB;
    const int c0   = __builtin_amdgcn_readfirstlane(g * 8);

    // ---------------- phase 0: stage Wk -> LDS [cg][ci][t][d16] -------------
    {
        const int d  = tid & 15;
        const int cA = tid >> 4;           // [0,32)
#pragma unroll
        for (int half = 0; half < 2; ++half) {
            const int c   = cA + half * 32;
            const int dst = (c >> 3) * 1152 + (c & 7) * 144 + d;
            const float* src = Wk + (d * CC + c) * 9;
#pragma unroll
            for (int t = 0; t < 9; ++t)
                lds[dst + t * 16] = src[t];
        }
    }
    __syncthreads();

    // ---------------- phase 1: packed partial k, 8 channels, 2 px ----------
    floatx2 aP0[8], aP1[8];                // [d-pair] per pixel
#pragma unroll
    for (int i = 0; i < 8; ++i) { aP0[i] = (floatx2){0.f, 0.f}; aP1[i] = (floatx2){0.f, 0.f}; }

    auto load3 = [&](floatx4 (&f)[3], int so) {
#pragma unroll
        for (int r = 0; r < 3; ++r)
            f[r] = llvm_amdgcn_raw_buffer_load_v4f32(rx, rowB[r], so, 0);
    };
    // 4 tap columns per row: s0 = w0-1 (masked), s1 = w0, s2 = w0+1, s3 = w0+2 (masked)
    auto mktaps = [&](const floatx4& f, float (&s)[4]) {
        s[0] = f.x * mL;
        s[1] = w0e ? f.x : f.y;
        s[2] = w0e ? f.y : f.z;
        s[3] = (w0e ? f.z : f.w) * mR;
    };
    auto compute = [&](const floatx4 (&f)[3], int wb) {
        float s[3][4];
#pragma unroll
        for (int r = 0; r < 3; ++r) mktaps(f[r], s[r]);
#pragma unroll
        for (int t = 0; t < 9; ++t) {
            const int tr = t / 3, tc = t % 3;
            const floatx2 t0 = {s[tr][tc],     s[tr][tc]};
            const floatx2 t1 = {s[tr][tc + 1], s[tr][tc + 1]};
#pragma unroll
            for (int j = 0; j < 4; ++j) {    // uniform ds_read_b128
                const floatx4 w4 = *(const floatx4*)&lds[wb + t * 16 + j * 4];
                const floatx2 lo = __builtin_shufflevector(w4, w4, 0, 1);
                const floatx2 hi = __builtin_shufflevector(w4, w4, 2, 3);
                aP0[2 * j + 0] = __builtin_elementwise_fma(lo, t0, aP0[2 * j + 0]);
                aP0[2 * j + 1] = __builtin_elementwise_fma(hi, t0, aP0[2 * j + 1]);
                aP1[2 * j + 0] = __builtin_elementwise_fma(lo, t1, aP1[2 * j + 0]);
                aP1[2 * j + 1] = __builtin_elementwise_fma(hi, t1, aP1[2 * j + 1]);
            }
        }
    };

    const int wbase = g * 1152;
    floatx4 f0[3], f1[3];
    load3(f0, base + c0 * HWB);
#pragma unroll
    for (int cp = 0; cp < 4; ++cp) {
        load3(f1, base + (c0 + 2 * cp + 1) * HWB);       // prefetch odd channel
        compute(f0, wbase + (2 * cp) * 144);
        load3(f0, base + (c0 + 2 * cp + 2) * HWB);       // prefetch next even (tail SRD-bounded)
        compute(f1, wbase + (2 * cp + 1) * 144);
    }
    __syncthreads();                                     // weight reads done

    // partials [g][d][p]: (p0, p0+1) contiguous -> b64 writes
#pragma unroll
    for (int i = 0; i < 8; ++i) {
        *(floatx2*)&lds[g * 2048 + (2 * i + 0) * 128 + p0] = (floatx2){aP0[i].x, aP1[i].x};
        *(floatx2*)&lds[g * 2048 + (2 * i + 1) * 128 + p0] = (floatx2){aP0[i].y, aP1[i].y};
    }
    __syncthreads();

    // ---------------- reduce 8 partials -> k[d][p] (in place) ---------------
#pragma unroll
    for (int rep = 0; rep < 4; ++rep) {
        const int idx = tid + rep * 512;                 // = d*128 + p
        float s = lds[idx];
#pragma unroll
        for (int gg = 1; gg < 8; ++gg) s += lds[gg * 2048 + idx];
        const int d = idx >> 7;                          // wave-uniform
        lds[idx] = fmaxf(s + bk[d], 0.f) * KLOG2E;
    }
    __syncthreads();

    // ---------------- phase 2: q, v, softmax, packed over pixel pair --------
    floatx2 kl2[16];                                     // k for both pixels, hoisted
#pragma unroll
    for (int d = 0; d < KD; ++d)
        kl2[d] = *(const floatx2*)&lds[d * 128 + p0];

    auto process = [&](const floatx4 (&f)[3], floatx2 z2, int c) {
        const float* wq = Wq + c * 9;                    // uniform -> s_load
        float s[3][4];
#pragma unroll
        for (int r = 0; r < 3; ++r) mktaps(f[r], s[r]);
        floatx2 q2 = {bq[c], bq[c]};
#pragma unroll
        for (int t = 0; t < 9; ++t) {
            const int tr = t / 3, tc = t % 3;
            const floatx2 tp2 = {s[tr][tc], s[tr][tc + 1]};
            const floatx2 wq2 = {wq[t], wq[t]};
            q2 = __builtin_elementwise_fma(wq2, tp2, q2);
        }
        const floatx2 zero2 = {0.f, 0.f};
        q2 = __builtin_elementwise_max(q2, zero2);

        floatx2 num2 = zero2, den2 = zero2;
#pragma unroll
        for (int d = 0; d < KD; ++d) {
            const floatx2 s2 = q2 * kl2[d];              // v_pk_mul_f32
            floatx2 e2;
            e2.x = FAST_EXP2(s2.x);
            e2.y = FAST_EXP2(s2.y);
            const floatx2 wv2 = {wv[d], wv[d]};
            const floatx2 bv2 = {bv[d], bv[d]};
            const floatx2 v2 = __builtin_elementwise_max(
                __builtin_elementwise_fma(z2, wv2, bv2), zero2);
            num2 = __builtin_elementwise_fma(e2, v2, num2);
            den2 = den2 + e2;
        }
        floatx2 o2;
        o2.x = __fdividef(num2.x, den2.x);
        o2.y = __fdividef(num2.y, den2.y);
        *(floatx2*)&out[(size_t)b * CC * HW + (size_t)c * HW + pix] = o2;
    };

    floatx4 fy0[3], fy1[3];
    floatx2 z0, z1;
    auto load3y = [&](floatx4 (&f)[3], floatx2& zz, int so) {
#pragma unroll
        for (int r = 0; r < 3; ++r)
            f[r] = llvm_amdgcn_raw_buffer_load_v4f32(ry, rowB[r], so, 0);
        zz = llvm_amdgcn_raw_buffer_load_v2f32(rz, pix * 4, so, 0);
    };

    load3y(fy0, z0, base + c0 * HWB);
#pragma unroll
    for (int cp = 0; cp < 4; ++cp) {
        load3y(fy1, z1, base + (c0 + 2 * cp + 1) * HWB);
        process(fy0, z0, c0 + 2 * cp);
        load3y(fy0, z0, base + (c0 + 2 * cp + 2) * HWB); // tail SRD-bounded
        process(fy1, z1, c0 + 2 * cp + 1);
    }
}

extern "C" void kernel_launch(void* const* d_in, const int* in_sizes, int n_in,
                              void* d_out, int out_size, void* d_ws, size_t ws_size,
                              hipStream_t stream) {
    const float* x  = (const float*)d_in[0];
    const float* y  = (const float*)d_in[1];
    const float* z  = (const float*)d_in[2];
    const float* Wq = (const float*)d_in[3];
    const float* bq = (const float*)d_in[4];
    const float* Wk = (const float*)d_in[5];
    const float* bk = (const float*)d_in[6];
    const float* wv = (const float*)d_in[7];
    const float* bv = (const float*)d_in[8];
    float* out = (float*)d_out;

    dim3 grid(WW / 32, HH / 4, 4);   // (4, 32, 4) = 512 blocks = 2/CU
    dim3 block(512);                 // 8 waves
    hipLaunchKernelGGL(gatev_fused, grid, block, 0, stream,
                       x, y, z, Wq, bq, Wk, bk, wv, bv, out);
}